// Round 1
// baseline (18548.611 us; speedup 1.0000x reference)
//
#include <hip/hip_runtime.h>

// Jordan RNN collapsed recurrence:
//   z_t = Wx@x_t + bh  (parallel GEMM)
//   h_1 = tanh(z_1); h_t = tanh(z_t + (Wh@Wy) h_{t-1} + Wh@by), t>=2  (sequential, coop kernel)
//   Y   = H@Wy^T + by  (parallel GEMM)
// ws layout (needs ~117.6 MB):
//   [0,16M)    Whb   bf16 4096x2048
//   [16M,32M)  WyTb  bf16 4096x2048 (Wy transposed)
//   [32M,48M)  Wyb   bf16 2048x4096
//   [48M,64M)  Zb    bf16 2048x4096 (z incl. bh)
//   [64M,80M)  Hb    bf16 2048x4096
//   [80M,104M) xb/Wxb (dead after Z gemm) overlapped by Wmb bf16 4096x4096 [80M,112M)
//   [112M]     cvec f32[4096]; [112M+64K] counter u32

#define T_STEPS 2048
#define HID 4096
#define NIN 2048
#define NOUT 2048

typedef unsigned short u16;
typedef unsigned int u32;
typedef __attribute__((ext_vector_type(8))) short bf16x8;
typedef __attribute__((ext_vector_type(4))) float f32x4;

__device__ __forceinline__ u16 f2b(float f) {
  u32 u = __float_as_uint(f);
  u32 r = (u + 0x7fffu + ((u >> 16) & 1u)) >> 16;  // RNE
  return (u16)r;
}
__device__ __forceinline__ float b2f(u16 h) { return __uint_as_float(((u32)h) << 16); }

// ---------------- f32 -> bf16 convert (vectorized) ----------------
__global__ void conv_kernel(const float* __restrict__ in, u16* __restrict__ out, int n4) {
  int stride = gridDim.x * blockDim.x;
  for (int i = blockIdx.x * blockDim.x + threadIdx.x; i < n4; i += stride) {
    float4 v = *reinterpret_cast<const float4*>(in + (size_t)i * 4);
    uint2 p;
    p.x = (u32)f2b(v.x) | ((u32)f2b(v.y) << 16);
    p.y = (u32)f2b(v.z) | ((u32)f2b(v.w) << 16);
    *reinterpret_cast<uint2*>(out + (size_t)i * 4) = p;
  }
}

// ------------- transpose+convert: in [R][C] f32 -> out [C][R] bf16 -------------
__global__ void transpose_conv(const float* __restrict__ in, u16* __restrict__ out, int R, int C) {
  __shared__ float tile[32][33];
  int bx = blockIdx.x * 32;  // along C
  int by = blockIdx.y * 32;  // along R
  int tx = threadIdx.x & 31, ty = threadIdx.x >> 5;
#pragma unroll
  for (int k = 0; k < 32; k += 8)
    tile[ty + k][tx] = in[(size_t)(by + ty + k) * C + bx + tx];
  __syncthreads();
#pragma unroll
  for (int k = 0; k < 32; k += 8)
    out[(size_t)(bx + ty + k) * R + by + tx] = f2b(tile[tx][ty + k]);
}

// ---------------- cvec = Wh @ by (f32, exact) ----------------
__global__ void cvec_kernel(const float* __restrict__ Wh, const float* __restrict__ by,
                            float* __restrict__ c) {
  int k = blockIdx.x, l = threadIdx.x;
  float s = 0.f;
  for (int i = l; i < NOUT; i += 64) s += Wh[(size_t)k * NOUT + i] * by[i];
#pragma unroll
  for (int m = 32; m; m >>= 1) s += __shfl_xor(s, m, 64);
  if (l == 0) c[k] = s;
}

// ---------------- bf16 GEMM: C[M][N] = A[M][K] @ Bt[N][K]^T (+bias[col]) ----------------
// 64x64 tile, 4 waves (one 16-row stripe each), mfma_f32_16x16x32_bf16.
// A-frag: a[j]=A[lane&15][ (lane>>4)*8 + j ]; B-frag: b[j]=B[k][col]=Bt[col][k];
// C/D: c[r] = C[(lane>>4)*4+r][lane&15]  (verified layouts per guide §3)
__global__ __launch_bounds__(256) void gemm_bt(
    const u16* __restrict__ A, const u16* __restrict__ Bt,
    int M, int N, int K,
    float* __restrict__ Cf, u16* __restrict__ Cb,
    const float* __restrict__ bias) {
  __shared__ __align__(16) u16 As[64][40];  // +8 u16 pad: keeps 16B align, kills conflicts
  __shared__ __align__(16) u16 Bs[64][40];
  const int tid = threadIdx.x;
  const int wave = tid >> 6;
  const int lane = tid & 63;
  const int m0 = blockIdx.y * 64;
  const int n0 = blockIdx.x * 64;
  const int lr = tid >> 2;
  const int lc = (tid & 3) << 3;
  const int frow = lane & 15;
  const int koff = (lane >> 4) << 3;

  f32x4 acc0 = {0.f, 0.f, 0.f, 0.f};
  f32x4 acc1 = acc0, acc2 = acc0, acc3 = acc0;

  const u16* pA = A + (size_t)(m0 + lr) * K + lc;
  const u16* pB = Bt + (size_t)(n0 + lr) * K + lc;

  for (int k0 = 0; k0 < K; k0 += 32) {
    uint4 va = *reinterpret_cast<const uint4*>(pA + k0);
    uint4 vb = *reinterpret_cast<const uint4*>(pB + k0);
    *reinterpret_cast<uint4*>(&As[lr][lc]) = va;
    *reinterpret_cast<uint4*>(&Bs[lr][lc]) = vb;
    __syncthreads();
    bf16x8 af = *reinterpret_cast<const bf16x8*>(&As[(wave << 4) + frow][koff]);
    bf16x8 b0 = *reinterpret_cast<const bf16x8*>(&Bs[frow][koff]);
    bf16x8 b1 = *reinterpret_cast<const bf16x8*>(&Bs[16 + frow][koff]);
    bf16x8 b2 = *reinterpret_cast<const bf16x8*>(&Bs[32 + frow][koff]);
    bf16x8 b3 = *reinterpret_cast<const bf16x8*>(&Bs[48 + frow][koff]);
    acc0 = __builtin_amdgcn_mfma_f32_16x16x32_bf16(af, b0, acc0, 0, 0, 0);
    acc1 = __builtin_amdgcn_mfma_f32_16x16x32_bf16(af, b1, acc1, 0, 0, 0);
    acc2 = __builtin_amdgcn_mfma_f32_16x16x32_bf16(af, b2, acc2, 0, 0, 0);
    acc3 = __builtin_amdgcn_mfma_f32_16x16x32_bf16(af, b3, acc3, 0, 0, 0);
    __syncthreads();
  }

  const int crow = m0 + (wave << 4) + ((lane >> 4) << 2);
  const int ccol = n0 + (lane & 15);
  float bv0 = bias ? bias[ccol] : 0.f;
  float bv1 = bias ? bias[ccol + 16] : 0.f;
  float bv2 = bias ? bias[ccol + 32] : 0.f;
  float bv3 = bias ? bias[ccol + 48] : 0.f;
  if (Cf) {
#pragma unroll
    for (int r = 0; r < 4; ++r) {
      size_t base = (size_t)(crow + r) * N + ccol;
      Cf[base] = acc0[r] + bv0;
      Cf[base + 16] = acc1[r] + bv1;
      Cf[base + 32] = acc2[r] + bv2;
      Cf[base + 48] = acc3[r] + bv3;
    }
  } else {
#pragma unroll
    for (int r = 0; r < 4; ++r) {
      size_t base = (size_t)(crow + r) * N + ccol;
      Cb[base] = f2b(acc0[r] + bv0);
      Cb[base + 16] = f2b(acc1[r] + bv1);
      Cb[base + 32] = f2b(acc2[r] + bv2);
      Cb[base + 48] = f2b(acc3[r] + bv3);
    }
  }
}

// ---------------- sequential recurrence (cooperative, persistent) ----------------
// 256 blocks x 512 threads. Block b owns rows [16b,16b+16) of W (f32 in registers).
// Thread t owns cols [8t,8t+8). Per step: poll counter, L3 atomic-load h row,
// 128 FMA, LDS-transpose reduce (512 partials -> 16 rows), tanh, bf16 store,
// one release atomicAdd per block.
__global__ __launch_bounds__(512, 2) void seq_kernel(
    const u16* __restrict__ Wm, const u16* __restrict__ Zb,
    const float* __restrict__ cvec, u16* __restrict__ H,
    u32* cnt, int T) {
  const int tid = threadIdx.x;
  const int b = blockIdx.x;
  const int r0 = b * 16;

  float w[16][8];
  {
    const u16* wp = Wm + (size_t)r0 * HID + tid * 8;
#pragma unroll
    for (int r = 0; r < 16; ++r) {
      uint4 q = *reinterpret_cast<const uint4*>(wp + (size_t)r * HID);
      w[r][0] = __uint_as_float(q.x << 16);
      w[r][1] = __uint_as_float(q.x & 0xffff0000u);
      w[r][2] = __uint_as_float(q.y << 16);
      w[r][3] = __uint_as_float(q.y & 0xffff0000u);
      w[r][4] = __uint_as_float(q.z << 16);
      w[r][5] = __uint_as_float(q.z & 0xffff0000u);
      w[r][6] = __uint_as_float(q.w << 16);
      w[r][7] = __uint_as_float(q.w & 0xffff0000u);
    }
  }
  const int rgrp = tid >> 5;   // reduce-phase row 0..15
  const int ilane = tid & 31;  // reduce-phase lane 0..31
  const float c_r = cvec[r0 + rgrp];

  __shared__ float red[512][17];  // stride 17: conflict-free transpose reduce
  __shared__ float hl[16];

  const u32* Hu = reinterpret_cast<const u32*>(H);
  u32* Hw = reinterpret_cast<u32*>(H);

  for (int t = 1; t <= T; ++t) {
    // prefetch this block's z values (read-only, hides L3 latency under the poll)
    float zv = 0.f;
    if (ilane == 0) zv = b2f(Zb[(size_t)(t - 1) * HID + r0 + rgrp]);

    float acc[16];
#pragma unroll
    for (int r = 0; r < 16; ++r) acc[r] = 0.f;

    if (t >= 2) {
      if (tid == 0) {
        const u32 target = 256u * (u32)(t - 1);
        while (__hip_atomic_load(cnt, __ATOMIC_RELAXED, __HIP_MEMORY_SCOPE_AGENT) < target) {}
        __builtin_amdgcn_fence(__ATOMIC_ACQUIRE, "agent");
      }
      __syncthreads();
      // h_{t-1}: this thread's 8 cols as 4 u32 (bf16 pairs), L2-bypassing loads
      const u32* hrow = Hu + (size_t)(t - 2) * (HID / 2) + tid * 4;
      u32 q0 = __hip_atomic_load(hrow + 0, __ATOMIC_RELAXED, __HIP_MEMORY_SCOPE_AGENT);
      u32 q1 = __hip_atomic_load(hrow + 1, __ATOMIC_RELAXED, __HIP_MEMORY_SCOPE_AGENT);
      u32 q2 = __hip_atomic_load(hrow + 2, __ATOMIC_RELAXED, __HIP_MEMORY_SCOPE_AGENT);
      u32 q3 = __hip_atomic_load(hrow + 3, __ATOMIC_RELAXED, __HIP_MEMORY_SCOPE_AGENT);
      float h[8];
      h[0] = __uint_as_float(q0 << 16); h[1] = __uint_as_float(q0 & 0xffff0000u);
      h[2] = __uint_as_float(q1 << 16); h[3] = __uint_as_float(q1 & 0xffff0000u);
      h[4] = __uint_as_float(q2 << 16); h[5] = __uint_as_float(q2 & 0xffff0000u);
      h[6] = __uint_as_float(q3 << 16); h[7] = __uint_as_float(q3 & 0xffff0000u);
#pragma unroll
      for (int c = 0; c < 8; ++c) {
#pragma unroll
        for (int r = 0; r < 16; ++r) acc[r] = fmaf(w[r][c], h[c], acc[r]);
      }
    }

#pragma unroll
    for (int r = 0; r < 16; ++r) red[tid][r] = acc[r];
    __syncthreads();

    float s = 0.f;
#pragma unroll
    for (int p = 0; p < 16; ++p) s += red[ilane + 32 * p][rgrp];
    s += __shfl_xor(s, 16, 64);
    s += __shfl_xor(s, 8, 64);
    s += __shfl_xor(s, 4, 64);
    s += __shfl_xor(s, 2, 64);
    s += __shfl_xor(s, 1, 64);

    if (ilane == 0) {
      float pre = zv + s + ((t >= 2) ? c_r : 0.f);
      float ax = fabsf(pre);
      float e = __expf(2.f * ax);
      float th = 1.f - 2.f / (e + 1.f);  // |pre| large -> e=inf -> th=1 (no NaN)
      hl[rgrp] = (pre < 0.f) ? -th : th;
    }
    __syncthreads();

    if (tid < 8) {
      u32 pk = (u32)f2b(hl[2 * tid]) | ((u32)f2b(hl[2 * tid + 1]) << 16);
      __hip_atomic_store(Hw + (size_t)(t - 1) * (HID / 2) + (r0 >> 1) + tid, pk,
                         __ATOMIC_RELAXED, __HIP_MEMORY_SCOPE_AGENT);
    }
    __syncthreads();  // drains wave0's stores (vmcnt(0) before s_barrier)
    if (tid == 0)
      (void)__hip_atomic_fetch_add(cnt, 1u, __ATOMIC_RELEASE, __HIP_MEMORY_SCOPE_AGENT);
  }
}

extern "C" void kernel_launch(void* const* d_in, const int* in_sizes, int n_in,
                              void* d_out, int out_size, void* d_ws, size_t ws_size,
                              hipStream_t stream) {
  (void)in_sizes; (void)n_in; (void)out_size; (void)ws_size;
  const float* x  = (const float*)d_in[0];
  const float* Wx = (const float*)d_in[1];
  const float* Wh = (const float*)d_in[2];
  const float* Wy = (const float*)d_in[3];
  const float* bh = (const float*)d_in[4];
  const float* by = (const float*)d_in[5];
  float* out = (float*)d_out;

  char* ws = (char*)d_ws;
  const size_t MB = 1ull << 20;
  u16* Whb  = (u16*)(ws + 0 * MB);
  u16* WyTb = (u16*)(ws + 16 * MB);
  u16* Wyb  = (u16*)(ws + 32 * MB);
  u16* Zb   = (u16*)(ws + 48 * MB);
  u16* Hb   = (u16*)(ws + 64 * MB);
  u16* xb   = (u16*)(ws + 80 * MB);
  u16* Wxb  = (u16*)(ws + 88 * MB);
  u16* Wmb  = (u16*)(ws + 80 * MB);  // overlaps xb/Wxb; written only after Z GEMM
  float* cv = (float*)(ws + 112 * MB);
  u32* cnt  = (u32*)(ws + 112 * MB + 65536);

  conv_kernel<<<1024, 256, 0, stream>>>(x, xb, (T_STEPS * NIN) / 4);
  conv_kernel<<<1024, 256, 0, stream>>>(Wx, Wxb, (HID * NIN) / 4);
  conv_kernel<<<1024, 256, 0, stream>>>(Wh, Whb, (HID * NOUT) / 4);
  conv_kernel<<<1024, 256, 0, stream>>>(Wy, Wyb, (NOUT * HID) / 4);
  transpose_conv<<<dim3(HID / 32, NOUT / 32), 256, 0, stream>>>(Wy, WyTb, NOUT, HID);
  cvec_kernel<<<HID, 64, 0, stream>>>(Wh, by, cv);

  // Z[2048][4096] = x @ Wx^T + bh   (bf16 out)
  gemm_bt<<<dim3(HID / 64, T_STEPS / 64), 256, 0, stream>>>(
      xb, Wxb, T_STEPS, HID, NIN, nullptr, Zb, bh);
  // Wm[4096][4096] = Wh @ Wy        (bf16 out; uses WyT for B^T form)
  gemm_bt<<<dim3(HID / 64, HID / 64), 256, 0, stream>>>(
      Whb, WyTb, HID, HID, NOUT, nullptr, Wmb, nullptr);

  hipMemsetAsync(cnt, 0, sizeof(u32), stream);
  int T = T_STEPS;
  void* args[] = {(void*)&Wmb, (void*)&Zb, (void*)&cv, (void*)&Hb, (void*)&cnt, (void*)&T};
  hipLaunchCooperativeKernel((const void*)seq_kernel, dim3(256), dim3(512), args, 0, stream);

  // Y[2048][2048] = H @ Wy^T + by   (f32 out -> d_out)
  gemm_bt<<<dim3(NOUT / 64, T_STEPS / 64), 256, 0, stream>>>(
      Hb, Wyb, T_STEPS, NOUT, HID, out, nullptr, by);
}

// Round 3
// 4582.621 us; speedup vs baseline: 4.0476x; 4.0476x over previous
//
#include <hip/hip_runtime.h>

// Jordan RNN collapsed recurrence:
//   z_t = Wx@x_t + bh  (parallel GEMM)
//   h_1 = tanh(z_1); h_t = tanh(z_t + (Wh@Wy) h_{t-1} + Wh@by), t>=2  (sequential, persistent)
//   Y   = H@Wy^T + by  (parallel GEMM)
// Sequential sync is DATA-AS-FLAG: H pre-poisoned with bf16-pair sentinel 0x7F807F80
// (tanh output can never be inf); consumers spin on their own 16B chunk of h.
// No atomic RMWs, no fences, no grid barrier.
// ws layout (~117.6 MB):
//   [0,16M)    Whb   bf16 4096x2048
//   [16M,32M)  WyTb  bf16 4096x2048 (Wy transposed)
//   [32M,48M)  Wyb   bf16 2048x4096
//   [48M,64M)  Zb    bf16 2048x4096 (z incl. bh)
//   [64M,80M)  Hb    bf16 2048x4096 (sentinel-poisoned before seq kernel)
//   [80M,104M) xb/Wxb (dead after Z gemm) overlapped by Wmb bf16 4096x4096 [80M,112M)
//   [112M]     cvec f32[4096]

#define T_STEPS 2048
#define HID 4096
#define NIN 2048
#define NOUT 2048
#define SENT 0x7F807F80u

typedef unsigned short u16;
typedef unsigned int u32;
typedef __attribute__((ext_vector_type(8))) short bf16x8;
typedef __attribute__((ext_vector_type(4))) float f32x4;

__device__ __forceinline__ u16 f2b(float f) {
  u32 u = __float_as_uint(f);
  u32 r = (u + 0x7fffu + ((u >> 16) & 1u)) >> 16;  // RNE
  return (u16)r;
}
__device__ __forceinline__ float b2f(u16 h) { return __uint_as_float(((u32)h) << 16); }

// ---------------- f32 -> bf16 convert (vectorized; 4 f32 per iter) ----------------
__global__ void conv_kernel(const float* __restrict__ in, u16* __restrict__ out, int n4) {
  int stride = gridDim.x * blockDim.x;
  for (int i = blockIdx.x * blockDim.x + threadIdx.x; i < n4; i += stride) {
    float4 v = *reinterpret_cast<const float4*>(in + (size_t)i * 4);
    uint2 p;
    p.x = (u32)f2b(v.x) | ((u32)f2b(v.y) << 16);
    p.y = (u32)f2b(v.z) | ((u32)f2b(v.w) << 16);
    *reinterpret_cast<uint2*>(out + (size_t)i * 4) = p;
  }
}

// ---------------- pattern fill (H sentinel poison; 16B = one uint4 per iter) ----------------
__global__ void fill_kernel(u32* __restrict__ p, u32 val, int n16) {
  int stride = gridDim.x * blockDim.x;
  uint4 v = {val, val, val, val};
  for (int i = blockIdx.x * blockDim.x + threadIdx.x; i < n16; i += stride)
    reinterpret_cast<uint4*>(p)[i] = v;
}

// ------------- transpose+convert: in [R][C] f32 -> out [C][R] bf16 -------------
__global__ void transpose_conv(const float* __restrict__ in, u16* __restrict__ out, int R, int C) {
  __shared__ float tile[32][33];
  int bx = blockIdx.x * 32;  // along C
  int by = blockIdx.y * 32;  // along R
  int tx = threadIdx.x & 31, ty = threadIdx.x >> 5;
#pragma unroll
  for (int k = 0; k < 32; k += 8)
    tile[ty + k][tx] = in[(size_t)(by + ty + k) * C + bx + tx];
  __syncthreads();
#pragma unroll
  for (int k = 0; k < 32; k += 8)
    out[(size_t)(bx + ty + k) * R + by + tx] = f2b(tile[tx][ty + k]);
}

// ---------------- cvec = Wh @ by (f32, exact) ----------------
__global__ void cvec_kernel(const float* __restrict__ Wh, const float* __restrict__ by,
                            float* __restrict__ c) {
  int k = blockIdx.x, l = threadIdx.x;
  float s = 0.f;
  for (int i = l; i < NOUT; i += 64) s += Wh[(size_t)k * NOUT + i] * by[i];
#pragma unroll
  for (int m = 32; m; m >>= 1) s += __shfl_xor(s, m, 64);
  if (l == 0) c[k] = s;
}

// ---------------- bf16 GEMM: C[M][N] = A[M][K] @ Bt[N][K]^T (+bias[col]) ----------------
__global__ __launch_bounds__(256) void gemm_bt(
    const u16* __restrict__ A, const u16* __restrict__ Bt,
    int M, int N, int K,
    float* __restrict__ Cf, u16* __restrict__ Cb,
    const float* __restrict__ bias) {
  __shared__ __align__(16) u16 As[64][40];
  __shared__ __align__(16) u16 Bs[64][40];
  const int tid = threadIdx.x;
  const int wave = tid >> 6;
  const int lane = tid & 63;
  const int m0 = blockIdx.y * 64;
  const int n0 = blockIdx.x * 64;
  const int lr = tid >> 2;
  const int lc = (tid & 3) << 3;
  const int frow = lane & 15;
  const int koff = (lane >> 4) << 3;

  f32x4 acc0 = {0.f, 0.f, 0.f, 0.f};
  f32x4 acc1 = acc0, acc2 = acc0, acc3 = acc0;

  const u16* pA = A + (size_t)(m0 + lr) * K + lc;
  const u16* pB = Bt + (size_t)(n0 + lr) * K + lc;

  for (int k0 = 0; k0 < K; k0 += 32) {
    uint4 va = *reinterpret_cast<const uint4*>(pA + k0);
    uint4 vb = *reinterpret_cast<const uint4*>(pB + k0);
    *reinterpret_cast<uint4*>(&As[lr][lc]) = va;
    *reinterpret_cast<uint4*>(&Bs[lr][lc]) = vb;
    __syncthreads();
    bf16x8 af = *reinterpret_cast<const bf16x8*>(&As[(wave << 4) + frow][koff]);
    bf16x8 b0 = *reinterpret_cast<const bf16x8*>(&Bs[frow][koff]);
    bf16x8 b1 = *reinterpret_cast<const bf16x8*>(&Bs[16 + frow][koff]);
    bf16x8 b2 = *reinterpret_cast<const bf16x8*>(&Bs[32 + frow][koff]);
    bf16x8 b3 = *reinterpret_cast<const bf16x8*>(&Bs[48 + frow][koff]);
    acc0 = __builtin_amdgcn_mfma_f32_16x16x32_bf16(af, b0, acc0, 0, 0, 0);
    acc1 = __builtin_amdgcn_mfma_f32_16x16x32_bf16(af, b1, acc1, 0, 0, 0);
    acc2 = __builtin_amdgcn_mfma_f32_16x16x32_bf16(af, b2, acc2, 0, 0, 0);
    acc3 = __builtin_amdgcn_mfma_f32_16x16x32_bf16(af, b3, acc3, 0, 0, 0);
    __syncthreads();
  }

  const int crow = m0 + (wave << 4) + ((lane >> 4) << 2);
  const int ccol = n0 + (lane & 15);
  float bv0 = bias ? bias[ccol] : 0.f;
  float bv1 = bias ? bias[ccol + 16] : 0.f;
  float bv2 = bias ? bias[ccol + 32] : 0.f;
  float bv3 = bias ? bias[ccol + 48] : 0.f;
  if (Cf) {
#pragma unroll
    for (int r = 0; r < 4; ++r) {
      size_t base = (size_t)(crow + r) * N + ccol;
      Cf[base] = acc0[r] + bv0;
      Cf[base + 16] = acc1[r] + bv1;
      Cf[base + 32] = acc2[r] + bv2;
      Cf[base + 48] = acc3[r] + bv3;
    }
  } else {
#pragma unroll
    for (int r = 0; r < 4; ++r) {
      size_t base = (size_t)(crow + r) * N + ccol;
      Cb[base] = f2b(acc0[r] + bv0);
      Cb[base + 16] = f2b(acc1[r] + bv1);
      Cb[base + 32] = f2b(acc2[r] + bv2);
      Cb[base + 48] = f2b(acc3[r] + bv3);
    }
  }
}

// ---------------- sequential recurrence (persistent, data-as-flag sync) ----------------
// 256 blocks x 512 threads. Block b owns rows [16b,16b+16) of W (f32 in registers).
// Thread t owns cols [8t,8t+8). Per step: spin on own 16B h chunk until != sentinel,
// 128 FMA, LDS-transpose reduce (512 partials -> 16 rows), tanh, bf16-pair store.
__global__ __launch_bounds__(512, 2) void seq_kernel(
    const u16* __restrict__ Wm, const u16* __restrict__ Zb,
    const float* __restrict__ cvec, u16* __restrict__ H, int T) {
  const int tid = threadIdx.x;
  const int b = blockIdx.x;
  const int r0 = b * 16;

  float w[16][8];
  {
    const u16* wp = Wm + (size_t)r0 * HID + tid * 8;
#pragma unroll
    for (int r = 0; r < 16; ++r) {
      uint4 q = *reinterpret_cast<const uint4*>(wp + (size_t)r * HID);
      w[r][0] = __uint_as_float(q.x << 16);
      w[r][1] = __uint_as_float(q.x & 0xffff0000u);
      w[r][2] = __uint_as_float(q.y << 16);
      w[r][3] = __uint_as_float(q.y & 0xffff0000u);
      w[r][4] = __uint_as_float(q.z << 16);
      w[r][5] = __uint_as_float(q.z & 0xffff0000u);
      w[r][6] = __uint_as_float(q.w << 16);
      w[r][7] = __uint_as_float(q.w & 0xffff0000u);
    }
  }
  const int rgrp = tid >> 5;   // reduce-phase row 0..15
  const int ilane = tid & 31;  // reduce-phase lane 0..31
  const int wv = tid >> 6;     // wave index 0..7
  const int lane = tid & 63;
  const float c_r = cvec[r0 + rgrp];

  __shared__ float red[512][17];  // stride 17: conflict-free transpose reduce

  const u32* Hu = reinterpret_cast<const u32*>(H);
  u32* Hw = reinterpret_cast<u32*>(H);

  for (int t = 1; t <= T; ++t) {
    // prefetch this block's z value (read-only; overlaps the spin below)
    float zv = 0.f;
    if (ilane == 0) zv = b2f(Zb[(size_t)(t - 1) * HID + r0 + rgrp]);

    float acc[16];
#pragma unroll
    for (int r = 0; r < 16; ++r) acc[r] = 0.f;

    if (t >= 2) {
      // spin on OWN 16B chunk of h_{t-1}: sentinel pair never occurs in tanh output
      const u32* hrow = Hu + (size_t)(t - 2) * (HID / 2) + tid * 4;
      u32 q0, q1, q2, q3;
      for (;;) {
        q0 = __hip_atomic_load(hrow + 0, __ATOMIC_RELAXED, __HIP_MEMORY_SCOPE_AGENT);
        q1 = __hip_atomic_load(hrow + 1, __ATOMIC_RELAXED, __HIP_MEMORY_SCOPE_AGENT);
        q2 = __hip_atomic_load(hrow + 2, __ATOMIC_RELAXED, __HIP_MEMORY_SCOPE_AGENT);
        q3 = __hip_atomic_load(hrow + 3, __ATOMIC_RELAXED, __HIP_MEMORY_SCOPE_AGENT);
        if (q0 != SENT && q1 != SENT && q2 != SENT && q3 != SENT) break;
      }
      float h[8];
      h[0] = __uint_as_float(q0 << 16); h[1] = __uint_as_float(q0 & 0xffff0000u);
      h[2] = __uint_as_float(q1 << 16); h[3] = __uint_as_float(q1 & 0xffff0000u);
      h[4] = __uint_as_float(q2 << 16); h[5] = __uint_as_float(q2 & 0xffff0000u);
      h[6] = __uint_as_float(q3 << 16); h[7] = __uint_as_float(q3 & 0xffff0000u);
#pragma unroll
      for (int c = 0; c < 8; ++c) {
#pragma unroll
        for (int r = 0; r < 16; ++r) acc[r] = fmaf(w[r][c], h[c], acc[r]);
      }
    }

#pragma unroll
    for (int r = 0; r < 16; ++r) red[tid][r] = acc[r];
    __syncthreads();

    float s = 0.f;
#pragma unroll
    for (int p = 0; p < 16; ++p) s += red[ilane + 32 * p][rgrp];
    s += __shfl_xor(s, 16, 64);
    s += __shfl_xor(s, 8, 64);
    s += __shfl_xor(s, 4, 64);
    s += __shfl_xor(s, 2, 64);
    s += __shfl_xor(s, 1, 64);
    // all lanes now hold their half's full sum; lanes 0/32 of wave wv = rows r0+2wv, r0+2wv+1

    float pre = zv + s + ((t >= 2) ? c_r : 0.f);
    float ax = fabsf(pre);
    float e = __expf(2.f * ax);
    float th = 1.f - 2.f / (e + 1.f);  // |pre| large -> e=inf -> th=1 (no NaN)
    float hv = (pre < 0.f) ? -th : th;
    float hv2 = __shfl_xor(hv, 32, 64);  // partner row's value

    if (lane == 0) {
      u32 pk = (u32)f2b(hv) | ((u32)f2b(hv2) << 16);  // even row low, odd row high
      __hip_atomic_store(Hw + (size_t)(t - 1) * (HID / 2) + (r0 >> 1) + wv, pk,
                         __ATOMIC_RELAXED, __HIP_MEMORY_SCOPE_AGENT);
    }
    __syncthreads();  // protect red[] for next iteration
  }
}

extern "C" void kernel_launch(void* const* d_in, const int* in_sizes, int n_in,
                              void* d_out, int out_size, void* d_ws, size_t ws_size,
                              hipStream_t stream) {
  (void)in_sizes; (void)n_in; (void)out_size; (void)ws_size;
  const float* x  = (const float*)d_in[0];
  const float* Wx = (const float*)d_in[1];
  const float* Wh = (const float*)d_in[2];
  const float* Wy = (const float*)d_in[3];
  const float* bh = (const float*)d_in[4];
  const float* by = (const float*)d_in[5];
  float* out = (float*)d_out;

  char* ws = (char*)d_ws;
  const size_t MB = 1ull << 20;
  u16* Whb  = (u16*)(ws + 0 * MB);
  u16* WyTb = (u16*)(ws + 16 * MB);
  u16* Wyb  = (u16*)(ws + 32 * MB);
  u16* Zb   = (u16*)(ws + 48 * MB);
  u16* Hb   = (u16*)(ws + 64 * MB);
  u16* xb   = (u16*)(ws + 80 * MB);
  u16* Wxb  = (u16*)(ws + 88 * MB);
  u16* Wmb  = (u16*)(ws + 80 * MB);  // overlaps xb/Wxb; written only after Z GEMM
  float* cv = (float*)(ws + 112 * MB);

  conv_kernel<<<1024, 256, 0, stream>>>(x, xb, (T_STEPS * NIN) / 4);
  conv_kernel<<<1024, 256, 0, stream>>>(Wx, Wxb, (HID * NIN) / 4);
  conv_kernel<<<1024, 256, 0, stream>>>(Wh, Whb, (HID * NOUT) / 4);
  conv_kernel<<<1024, 256, 0, stream>>>(Wy, Wyb, (NOUT * HID) / 4);
  transpose_conv<<<dim3(HID / 32, NOUT / 32), 256, 0, stream>>>(Wy, WyTb, NOUT, HID);
  cvec_kernel<<<HID, 64, 0, stream>>>(Wh, by, cv);
  // poison H with bf16-pair sentinel: T*HID bf16 = T*HID/8 uint4 writes (16B each)
  fill_kernel<<<1024, 256, 0, stream>>>((u32*)Hb, SENT, (T_STEPS * HID) / 8);

  // Z[2048][4096] = x @ Wx^T + bh   (bf16 out)
  gemm_bt<<<dim3(HID / 64, T_STEPS / 64), 256, 0, stream>>>(
      xb, Wxb, T_STEPS, HID, NIN, nullptr, Zb, bh);
  // Wm[4096][4096] = Wh @ Wy        (bf16 out; uses WyT for B^T form)
  gemm_bt<<<dim3(HID / 64, HID / 64), 256, 0, stream>>>(
      Whb, WyTb, HID, HID, NOUT, nullptr, Wmb, nullptr);

  int T = T_STEPS;
  void* args[] = {(void*)&Wmb, (void*)&Zb, (void*)&cv, (void*)&Hb, (void*)&T};
  hipLaunchCooperativeKernel((const void*)seq_kernel, dim3(256), dim3(512), args, 0, stream);

  // Y[2048][2048] = H @ Wy^T + by   (f32 out -> d_out)
  gemm_bt<<<dim3(NOUT / 64, T_STEPS / 64), 256, 0, stream>>>(
      Hb, Wyb, T_STEPS, NOUT, HID, out, nullptr, by);
}